// Round 6
// baseline (693.242 us; speedup 1.0000x reference)
//
#include <hip/hip_runtime.h>

#define THRESH 0.5f
#define BAND   1e-3f

constexpr int N  = 8192;   // rows of fea1 / fea2
constexpr int FD = 128;    // feature dim
constexpr int WD = 64;     // embed dim (= K of similarity GEMMs)

typedef __attribute__((ext_vector_type(8)))  short short8;   // 8 bf16 = 4 VGPR
typedef __attribute__((ext_vector_type(4)))  float f32x4;    // MFMA 16x16 accum / stores

// f32 -> bf16 round-to-nearest-even
static __device__ __forceinline__ unsigned short f2bf(float x) {
  union { float f; unsigned u; } v; v.f = x;
  unsigned r = v.u + 0x7FFFu + ((v.u >> 16) & 1u);
  return (unsigned short)(r >> 16);
}
static __device__ __forceinline__ float bf2f(unsigned short h) {
  union { unsigned u; float f; } v; v.u = (unsigned)h << 16;
  return v.f;
}

// Exact f32 dot, same sequential fmaf k-order as the reference-matching path.
static __device__ __noinline__ float exact_dot(const float* __restrict__ a,
                                               const float* __restrict__ b) {
  float s = 0.f;
#pragma unroll 1
  for (int k = 0; k < WD; ++k) s = fmaf(a[k], b[k], s);
  return s;
}

// ---------------------------------------------------------------------------
// Kernel 1: embed = fea @ w, row-normalize. Outputs f32 (for exact fixup) AND
// bf16 hi/lo split (for MFMA). grid (N/32, 2), block 256.
// ---------------------------------------------------------------------------
__global__ __launch_bounds__(256) void embed_norm(
    const float* __restrict__ fea1, const float* __restrict__ fea2,
    const float* __restrict__ w1,   const float* __restrict__ w2,
    float* __restrict__ E1n, float* __restrict__ E2n,
    unsigned short* __restrict__ E1h, unsigned short* __restrict__ E1l,
    unsigned short* __restrict__ E2h, unsigned short* __restrict__ E2l) {
  const int which = blockIdx.y;
  const float* __restrict__ fea = which ? fea2 : fea1;
  const float* __restrict__ w   = which ? w2   : w1;
  float*          En = which ? E2n : E1n;
  unsigned short* Eh = which ? E2h : E1h;
  unsigned short* El = which ? E2l : E1l;

  __shared__ float wl[FD * WD];   // 32 KB
  __shared__ float fl[32][FD];    // 16 KB

  const int t    = threadIdx.x;
  const int row0 = blockIdx.x * 32;

#pragma unroll
  for (int i = 0; i < 8; ++i) {
    const int idx = (t + i * 256) * 4;
    *(float4*)&wl[idx] = *(const float4*)&w[idx];
  }
#pragma unroll
  for (int i = 0; i < 4; ++i) {
    const int idx = t + i * 256;
    const int r = idx >> 5;
    const int c = (idx & 31) * 4;
    *(float4*)&fl[r][c] = *(const float4*)&fea[(size_t)(row0 + r) * FD + c];
  }
  __syncthreads();

  const int wave = t >> 6, lane = t & 63;
#pragma unroll 1
  for (int rr = 0; rr < 8; ++rr) {
    const int r = wave * 8 + rr;
    float acc = 0.f;
#pragma unroll 16
    for (int k = 0; k < FD; ++k)
      acc = fmaf(fl[r][k], wl[k * WD + lane], acc);
    float ss = acc * acc;
#pragma unroll
    for (int m = 32; m >= 1; m >>= 1) ss += __shfl_xor(ss, m, 64);
    const float scale = 1.f / fmaxf(sqrtf(ss), 1e-8f);
    const float e = acc * scale;
    const size_t o = (size_t)(row0 + r) * WD + lane;
    En[o] = e;
    const unsigned short h = f2bf(e);
    Eh[o] = h;
    El[o] = f2bf(e - bf2f(h));
  }
}

// ---------------------------------------------------------------------------
// Kernel 2: both planes via bf16 hi/lo MFMA, swapped operands (lane's 4 accum
// regs = 4 consecutive C-columns of one row). d_out is pre-zeroed by
// hipMemsetAsync at fill-rate (6.2 TB/s), so this kernel stores ONLY
// fragments containing a value >= THRESH (~1% of store instructions survive
// the exec mask; sim ~ N(0,1/64) => P(>=0.5) ~ 3e-5 + plane-1 diagonal).
// Borderline |v-0.5|<BAND entries recomputed inline in exact f32.
// 128x128 tile/block, 4 waves of 64x64. grid (64,64), block 256. No LDS.
// ---------------------------------------------------------------------------
__global__ __launch_bounds__(256) void sim_mfma(
    const unsigned short* __restrict__ E1h, const unsigned short* __restrict__ E1l,
    const unsigned short* __restrict__ E2h, const unsigned short* __restrict__ E2l,
    const float* __restrict__ E1n, const float* __restrict__ E2n,
    float* __restrict__ out) {
  const int bi = blockIdx.y, bj = blockIdx.x;
  const int t = threadIdx.x, w = t >> 6, lane = t & 63;
  const int wr = w >> 1, wc = w & 1;
  const int row0 = bi * 128 + wr * 64;   // m range (C rows, E1 side)
  const int col0 = bj * 128 + wc * 64;   // n range (C cols, E2/E1 side)
  const int fr = lane & 15;
  const int fg = lane >> 4;

  // Y fragments (b-operand): E1 rows row0+ti*16+fr. Same for both planes.
  short8 yh[2][4], yl[2][4];
#pragma unroll
  for (int ks = 0; ks < 2; ++ks)
#pragma unroll
    for (int ti = 0; ti < 4; ++ti) {
      const size_t r = (size_t)(row0 + ti * 16 + fr) * WD + ks * 32 + fg * 8;
      yh[ks][ti] = *(const short8*)(E1h + r);
      yl[ks][ti] = *(const short8*)(E1l + r);
    }

#pragma unroll 1
  for (int plane = 0; plane < 2; ++plane) {
    const unsigned short* __restrict__ Xh = plane ? E1h : E2h;
    const unsigned short* __restrict__ Xl = plane ? E1l : E2l;
    const float*          __restrict__ Xn = plane ? E1n : E2n;

    f32x4 acc[4][4] = {};   // [tj (n-tile)][ti (m-tile)]
#pragma unroll
    for (int ks = 0; ks < 2; ++ks) {
      short8 xh[4], xl[4];
#pragma unroll
      for (int tj = 0; tj < 4; ++tj) {
        const size_t r = (size_t)(col0 + tj * 16 + fr) * WD + ks * 32 + fg * 8;
        xh[tj] = *(const short8*)(Xh + r);
        xl[tj] = *(const short8*)(Xl + r);
      }
#pragma unroll
      for (int tj = 0; tj < 4; ++tj)
#pragma unroll
        for (int ti = 0; ti < 4; ++ti) {
          acc[tj][ti] = __builtin_amdgcn_mfma_f32_16x16x32_bf16(xh[tj], yh[ks][ti], acc[tj][ti], 0, 0, 0);
          acc[tj][ti] = __builtin_amdgcn_mfma_f32_16x16x32_bf16(xh[tj], yl[ks][ti], acc[tj][ti], 0, 0, 0);
          acc[tj][ti] = __builtin_amdgcn_mfma_f32_16x16x32_bf16(xl[tj], yh[ks][ti], acc[tj][ti], 0, 0, 0);
          acc[tj][ti] = __builtin_amdgcn_mfma_f32_16x16x32_bf16(xl[tj], yl[ks][ti], acc[tj][ti], 0, 0, 0);
        }
    }

    // Epilogue: reg r holds C[m][nb+r]. Store only if some value survives
    // the threshold (output pre-zeroed by memset).
    float* __restrict__ o = out + (size_t)plane * N * N;
#pragma unroll
    for (int tj = 0; tj < 4; ++tj)
#pragma unroll
      for (int ti = 0; ti < 4; ++ti) {
        const int m  = row0 + ti * 16 + fr;
        const int nb = col0 + tj * 16 + fg * 4;
        const f32x4 v = acc[tj][ti];
        // cheap wave-uniform-ish prefilter: does this lane have any candidate?
        float mx = fmaxf(fmaxf(v[0], v[1]), fmaxf(v[2], v[3]));
        if (mx >= THRESH - BAND) {          // rare (~1% of lanes/instrs)
          f32x4 sv;
#pragma unroll
          for (int r = 0; r < 4; ++r) {
            float val = v[r];
            if (fabsf(val - THRESH) < BAND)
              val = exact_dot(E1n + (size_t)m * WD, Xn + (size_t)(nb + r) * WD);
            sv[r] = (val < THRESH) ? 0.f : val;
          }
          if (sv[0] > 0.f || sv[1] > 0.f || sv[2] > 0.f || sv[3] > 0.f)
            *(f32x4*)(o + (size_t)m * N + nb) = sv;
        }
      }
  }
}

extern "C" void kernel_launch(void* const* d_in, const int* in_sizes, int n_in,
                              void* d_out, int out_size, void* d_ws, size_t ws_size,
                              hipStream_t stream) {
  const float* fea1 = (const float*)d_in[0];
  const float* fea2 = (const float*)d_in[1];
  const float* w1   = (const float*)d_in[2];
  const float* w2   = (const float*)d_in[3];
  float* out = (float*)d_out;

  char* ws = (char*)d_ws;
  float*          E1n = (float*)(ws);                         // 2 MB
  float*          E2n = (float*)(ws + (2u << 20));            // 2 MB
  unsigned short* E1h = (unsigned short*)(ws + (4u << 20));   // 1 MB
  unsigned short* E1l = (unsigned short*)(ws + (5u << 20));   // 1 MB
  unsigned short* E2h = (unsigned short*)(ws + (6u << 20));   // 1 MB
  unsigned short* E2l = (unsigned short*)(ws + (7u << 20));   // 1 MB

  embed_norm<<<dim3(N / 32, 2), 256, 0, stream>>>(
      fea1, fea2, w1, w2, E1n, E2n, E1h, E1l, E2h, E2l);
  // Zero the full output at fill rate (~86 us for 537 MB); the sim kernel
  // then writes only the rare >= THRESH fragments.
  hipMemsetAsync(out, 0, (size_t)2 * N * N * sizeof(float), stream);
  sim_mfma<<<dim3(64, 64), 256, 0, stream>>>(
      E1h, E1l, E2h, E2l, E1n, E2n, out);
}

// Round 7
// 639.605 us; speedup vs baseline: 1.0839x; 1.0839x over previous
//
#include <hip/hip_runtime.h>

#define THRESH 0.5f
#define BAND   1e-3f

constexpr int N  = 8192;   // rows of fea1 / fea2
constexpr int FD = 128;    // feature dim
constexpr int WD = 64;     // embed dim (= K of similarity GEMMs)

typedef __attribute__((ext_vector_type(8)))  short short8;   // 8 bf16 = 4 VGPR
typedef __attribute__((ext_vector_type(4)))  float f32x4;    // MFMA 16x16 accum / stores

// f32 -> bf16 round-to-nearest-even
static __device__ __forceinline__ unsigned short f2bf(float x) {
  union { float f; unsigned u; } v; v.f = x;
  unsigned r = v.u + 0x7FFFu + ((v.u >> 16) & 1u);
  return (unsigned short)(r >> 16);
}
static __device__ __forceinline__ float bf2f(unsigned short h) {
  union { unsigned u; float f; } v; v.u = (unsigned)h << 16;
  return v.f;
}

// Exact f32 dot, same sequential fmaf k-order as the reference-matching path.
static __device__ __noinline__ float exact_dot(const float* __restrict__ a,
                                               const float* __restrict__ b) {
  float s = 0.f;
#pragma unroll 1
  for (int k = 0; k < WD; ++k) s = fmaf(a[k], b[k], s);
  return s;
}

// ---------------------------------------------------------------------------
// Kernel 1: embed = fea @ w, row-normalize. Outputs f32 (for exact fixup) AND
// bf16 hi/lo split (for MFMA). grid (N/32, 2), block 256.
// ---------------------------------------------------------------------------
__global__ __launch_bounds__(256) void embed_norm(
    const float* __restrict__ fea1, const float* __restrict__ fea2,
    const float* __restrict__ w1,   const float* __restrict__ w2,
    float* __restrict__ E1n, float* __restrict__ E2n,
    unsigned short* __restrict__ E1h, unsigned short* __restrict__ E1l,
    unsigned short* __restrict__ E2h, unsigned short* __restrict__ E2l) {
  const int which = blockIdx.y;
  const float* __restrict__ fea = which ? fea2 : fea1;
  const float* __restrict__ w   = which ? w2   : w1;
  float*          En = which ? E2n : E1n;
  unsigned short* Eh = which ? E2h : E1h;
  unsigned short* El = which ? E2l : E1l;

  __shared__ float wl[FD * WD];   // 32 KB
  __shared__ float fl[32][FD];    // 16 KB

  const int t    = threadIdx.x;
  const int row0 = blockIdx.x * 32;

#pragma unroll
  for (int i = 0; i < 8; ++i) {
    const int idx = (t + i * 256) * 4;
    *(float4*)&wl[idx] = *(const float4*)&w[idx];
  }
#pragma unroll
  for (int i = 0; i < 4; ++i) {
    const int idx = t + i * 256;
    const int r = idx >> 5;
    const int c = (idx & 31) * 4;
    *(float4*)&fl[r][c] = *(const float4*)&fea[(size_t)(row0 + r) * FD + c];
  }
  __syncthreads();

  const int wave = t >> 6, lane = t & 63;
#pragma unroll 1
  for (int rr = 0; rr < 8; ++rr) {
    const int r = wave * 8 + rr;
    float acc = 0.f;
#pragma unroll 16
    for (int k = 0; k < FD; ++k)
      acc = fmaf(fl[r][k], wl[k * WD + lane], acc);
    float ss = acc * acc;
#pragma unroll
    for (int m = 32; m >= 1; m >>= 1) ss += __shfl_xor(ss, m, 64);
    const float scale = 1.f / fmaxf(sqrtf(ss), 1e-8f);
    const float e = acc * scale;
    const size_t o = (size_t)(row0 + r) * WD + lane;
    En[o] = e;
    const unsigned short h = f2bf(e);
    Eh[o] = h;
    El[o] = f2bf(e - bf2f(h));
  }
}

// ---------------------------------------------------------------------------
// Kernel 2: both planes via bf16 hi/lo MFMA, swapped operands (lane's 4 accum
// regs = 4 consecutive C-columns of one row -> f32x4 nt stores, R4 epilogue).
//
// NEW vs R4: bijective XCD-aware swizzle. Round 1-6 invariant: ~160-200 us
// regardless of store scheme => bottleneck is 786 MB of fragment re-reads
// served by Infinity Cache (E arrays written scattered across XCDs; per-XCD
// L2 can't cache remote-written lines on first read). Swizzle gives each XCD
// a fixed 1024-row A-panel (0.5 MB, L2-resident) and streams the B-side
// through its L2 once => reads become L2-hits after first touch.
//   lin = blockIdx.x in [0,4096); xcd = lin&7 (HW round-robin assumption)
//   bi  = (lin&7)*8 + ((lin>>3)&7)   -> XCD k owns bi in [8k, 8k+8)
//   bj  = lin>>6                     -> walks all 64 columns per XCD
// grid (4096), block 256 (4 waves of 64x64). No LDS.
// ---------------------------------------------------------------------------
__global__ __launch_bounds__(256) void sim_mfma(
    const unsigned short* __restrict__ E1h, const unsigned short* __restrict__ E1l,
    const unsigned short* __restrict__ E2h, const unsigned short* __restrict__ E2l,
    const float* __restrict__ E1n, const float* __restrict__ E2n,
    float* __restrict__ out) {
  const int lin = blockIdx.x;
  const int bi = (lin & 7) * 8 + ((lin >> 3) & 7);
  const int bj = lin >> 6;

  const int t = threadIdx.x, w = t >> 6, lane = t & 63;
  const int wr = w >> 1, wc = w & 1;
  const int row0 = bi * 128 + wr * 64;   // m range (C rows, E1 side)
  const int col0 = bj * 128 + wc * 64;   // n range (C cols, E2/E1 side)
  const int fr = lane & 15;
  const int fg = lane >> 4;

  // Y fragments (b-operand): E1 rows row0+ti*16+fr. Same for both planes.
  short8 yh[2][4], yl[2][4];
#pragma unroll
  for (int ks = 0; ks < 2; ++ks)
#pragma unroll
    for (int ti = 0; ti < 4; ++ti) {
      const size_t r = (size_t)(row0 + ti * 16 + fr) * WD + ks * 32 + fg * 8;
      yh[ks][ti] = *(const short8*)(E1h + r);
      yl[ks][ti] = *(const short8*)(E1l + r);
    }

#pragma unroll 1
  for (int plane = 0; plane < 2; ++plane) {
    const unsigned short* __restrict__ Xh = plane ? E1h : E2h;
    const unsigned short* __restrict__ Xl = plane ? E1l : E2l;
    const float*          __restrict__ Xn = plane ? E1n : E2n;

    f32x4 acc[4][4] = {};   // [tj (n-tile)][ti (m-tile)]
#pragma unroll
    for (int ks = 0; ks < 2; ++ks) {
      short8 xh[4], xl[4];
#pragma unroll
      for (int tj = 0; tj < 4; ++tj) {
        const size_t r = (size_t)(col0 + tj * 16 + fr) * WD + ks * 32 + fg * 8;
        xh[tj] = *(const short8*)(Xh + r);
        xl[tj] = *(const short8*)(Xl + r);
      }
#pragma unroll
      for (int tj = 0; tj < 4; ++tj)
#pragma unroll
        for (int ti = 0; ti < 4; ++ti) {
          acc[tj][ti] = __builtin_amdgcn_mfma_f32_16x16x32_bf16(xh[tj], yh[ks][ti], acc[tj][ti], 0, 0, 0);
          acc[tj][ti] = __builtin_amdgcn_mfma_f32_16x16x32_bf16(xh[tj], yl[ks][ti], acc[tj][ti], 0, 0, 0);
          acc[tj][ti] = __builtin_amdgcn_mfma_f32_16x16x32_bf16(xl[tj], yh[ks][ti], acc[tj][ti], 0, 0, 0);
          acc[tj][ti] = __builtin_amdgcn_mfma_f32_16x16x32_bf16(xl[tj], yl[ks][ti], acc[tj][ti], 0, 0, 0);
        }
    }

    // Epilogue (R4): reg r holds C[m][nb+r] -> f32x4 nontemporal store.
    float* __restrict__ o = out + (size_t)plane * N * N;
#pragma unroll
    for (int tj = 0; tj < 4; ++tj)
#pragma unroll
      for (int ti = 0; ti < 4; ++ti) {
        const int m  = row0 + ti * 16 + fr;
        const int nb = col0 + tj * 16 + fg * 4;
        const f32x4 v = acc[tj][ti];
        f32x4 sv;
#pragma unroll
        for (int r = 0; r < 4; ++r) {
          float val = v[r];
          if (fabsf(val - THRESH) < BAND)   // rare: exact f32 recompute
            val = exact_dot(E1n + (size_t)m * WD, Xn + (size_t)(nb + r) * WD);
          sv[r] = (val < THRESH) ? 0.f : val;
        }
        __builtin_nontemporal_store(sv, (f32x4*)(o + (size_t)m * N + nb));
      }
  }
}

extern "C" void kernel_launch(void* const* d_in, const int* in_sizes, int n_in,
                              void* d_out, int out_size, void* d_ws, size_t ws_size,
                              hipStream_t stream) {
  const float* fea1 = (const float*)d_in[0];
  const float* fea2 = (const float*)d_in[1];
  const float* w1   = (const float*)d_in[2];
  const float* w2   = (const float*)d_in[3];
  float* out = (float*)d_out;

  char* ws = (char*)d_ws;
  float*          E1n = (float*)(ws);                         // 2 MB
  float*          E2n = (float*)(ws + (2u << 20));            // 2 MB
  unsigned short* E1h = (unsigned short*)(ws + (4u << 20));   // 1 MB
  unsigned short* E1l = (unsigned short*)(ws + (5u << 20));   // 1 MB
  unsigned short* E2h = (unsigned short*)(ws + (6u << 20));   // 1 MB
  unsigned short* E2l = (unsigned short*)(ws + (7u << 20));   // 1 MB

  embed_norm<<<dim3(N / 32, 2), 256, 0, stream>>>(
      fea1, fea2, w1, w2, E1n, E2n, E1h, E1l, E2h, E2l);
  sim_mfma<<<4096, 256, 0, stream>>>(
      E1h, E1l, E2h, E2l, E1n, E2n, out);
}

// Round 8
// 630.753 us; speedup vs baseline: 1.0991x; 1.0140x over previous
//
#include <hip/hip_runtime.h>

#define THRESH 0.5f
#define BAND   1e-3f

constexpr int N  = 8192;   // rows of fea1 / fea2
constexpr int FD = 128;    // feature dim
constexpr int WD = 64;     // embed dim (= K of similarity GEMMs)

typedef __attribute__((ext_vector_type(8)))  short short8;   // 8 bf16 = 4 VGPR
typedef __attribute__((ext_vector_type(4)))  float f32x4;    // MFMA 16x16 accum / stores

// f32 -> bf16 round-to-nearest-even
static __device__ __forceinline__ unsigned short f2bf(float x) {
  union { float f; unsigned u; } v; v.f = x;
  unsigned r = v.u + 0x7FFFu + ((v.u >> 16) & 1u);
  return (unsigned short)(r >> 16);
}
static __device__ __forceinline__ float bf2f(unsigned short h) {
  union { unsigned u; float f; } v; v.u = (unsigned)h << 16;
  return v.f;
}

// Exact f32 dot, same sequential fmaf k-order as the reference-matching path.
static __device__ __noinline__ float exact_dot(const float* __restrict__ a,
                                               const float* __restrict__ b) {
  float s = 0.f;
#pragma unroll 1
  for (int k = 0; k < WD; ++k) s = fmaf(a[k], b[k], s);
  return s;
}

// ---------------------------------------------------------------------------
// Kernel 1: embed = fea @ w, row-normalize. Outputs f32 (for exact fixup) AND
// bf16 hi/lo split (for MFMA). grid (N/32, 2), block 256.
// ---------------------------------------------------------------------------
__global__ __launch_bounds__(256) void embed_norm(
    const float* __restrict__ fea1, const float* __restrict__ fea2,
    const float* __restrict__ w1,   const float* __restrict__ w2,
    float* __restrict__ E1n, float* __restrict__ E2n,
    unsigned short* __restrict__ E1h, unsigned short* __restrict__ E1l,
    unsigned short* __restrict__ E2h, unsigned short* __restrict__ E2l) {
  const int which = blockIdx.y;
  const float* __restrict__ fea = which ? fea2 : fea1;
  const float* __restrict__ w   = which ? w2   : w1;
  float*          En = which ? E2n : E1n;
  unsigned short* Eh = which ? E2h : E1h;
  unsigned short* El = which ? E2l : E1l;

  __shared__ float wl[FD * WD];   // 32 KB
  __shared__ float fl[32][FD];    // 16 KB

  const int t    = threadIdx.x;
  const int row0 = blockIdx.x * 32;

#pragma unroll
  for (int i = 0; i < 8; ++i) {
    const int idx = (t + i * 256) * 4;
    *(float4*)&wl[idx] = *(const float4*)&w[idx];
  }
#pragma unroll
  for (int i = 0; i < 4; ++i) {
    const int idx = t + i * 256;
    const int r = idx >> 5;
    const int c = (idx & 31) * 4;
    *(float4*)&fl[r][c] = *(const float4*)&fea[(size_t)(row0 + r) * FD + c];
  }
  __syncthreads();

  const int wave = t >> 6, lane = t & 63;
#pragma unroll 1
  for (int rr = 0; rr < 8; ++rr) {
    const int r = wave * 8 + rr;
    float acc = 0.f;
#pragma unroll 16
    for (int k = 0; k < FD; ++k)
      acc = fmaf(fl[r][k], wl[k * WD + lane], acc);
    float ss = acc * acc;
#pragma unroll
    for (int m = 32; m >= 1; m >>= 1) ss += __shfl_xor(ss, m, 64);
    const float scale = 1.f / fmaxf(sqrtf(ss), 1e-8f);
    const float e = acc * scale;
    const size_t o = (size_t)(row0 + r) * WD + lane;
    En[o] = e;
    const unsigned short h = f2bf(e);
    Eh[o] = h;
    El[o] = f2bf(e - bf2f(h));
  }
}

// ---------------------------------------------------------------------------
// Kernel 2: both planes via bf16 hi/lo MFMA, swapped operands, R4 epilogue
// (f32x4 nt stores).
//
// NEW vs R4: LDS staging. R1-R7 invariant ~160-180 us = 786 MB of logical
// fragment re-reads served by Infinity Cache (~5 TB/s): per-XCD working set
// (A-panel + both planes' B streams = 4.5 MB) exceeds the 4 MB L2, so L2
// thrashes regardless of block mapping (R7's swizzle null result). Fix:
// stage A(h,l) 32 KB + B(h,l) 32 KB per block in LDS (one global pass,
// 393 MB total) and serve all fragment re-reads from LDS.
// LDS layout XOR-swizzled: phys_byte = logical_byte ^ ((row&7)<<4), bits 4-6
// bijective within each 128B row -> both ds_write_b128 stage and
// ds_read_b128 fragment reads hit all 32 banks (8 b128 start positions x
// 8 lanes each = 1 KB/instr at floor; naive [row][128B] would be 16-way).
// 64 KB LDS -> 2 blocks/CU; stage phases overlap the other block's MFMA.
// grid (64,64), block 256 (4 waves of 64x64).
// ---------------------------------------------------------------------------
__global__ __launch_bounds__(256) void sim_mfma(
    const unsigned short* __restrict__ E1h, const unsigned short* __restrict__ E1l,
    const unsigned short* __restrict__ E2h, const unsigned short* __restrict__ E2l,
    const float* __restrict__ E1n, const float* __restrict__ E2n,
    float* __restrict__ out) {
  __shared__ __attribute__((aligned(16))) char smem[65536];
  char* const Ah = smem;              // 16 KB: E1h rows bi*128..+128
  char* const Al = smem + 16384;      // 16 KB: E1l
  char* const Bh = smem + 32768;      // 16 KB: plane B hi
  char* const Bl = smem + 49152;      // 16 KB: plane B lo

  const int bi = blockIdx.y, bj = blockIdx.x;
  const int t = threadIdx.x, w = t >> 6, lane = t & 63;
  const int wr = w >> 1, wc = w & 1;
  const int fr = lane & 15;
  const int fg = lane >> 4;

  // Stage one 16 KB panel (128 rows x 128 B, contiguous in global) into LDS
  // with the XOR swizzle. 1024 16B-chunks, 4 per thread.
  auto stage16k = [&](char* dst, const unsigned short* srcbase) {
    const char* src = (const char*)srcbase;
#pragma unroll
    for (int i = 0; i < 4; ++i) {
      const int c = t + i * 256;
      const int row = c >> 3, b = (c & 7) * 16;
      *(short8*)(dst + row * 128 + (b ^ ((row & 7) << 4))) =
          *(const short8*)(src + c * 16);
    }
  };

  stage16k(Ah, E1h + (size_t)bi * 128 * WD);
  stage16k(Al, E1l + (size_t)bi * 128 * WD);
  stage16k(Bh, E2h + (size_t)bj * 128 * WD);
  stage16k(Bl, E2l + (size_t)bj * 128 * WD);
  __syncthreads();

  // Y fragments (b-operand, E1 side) from A-LDS; kept in regs across planes.
  short8 yh[2][4], yl[2][4];
#pragma unroll
  for (int ks = 0; ks < 2; ++ks) {
    const int sw = (ks * 64 + fg * 16) ^ ((fr & 7) << 4);
#pragma unroll
    for (int ti = 0; ti < 4; ++ti) {
      const int off = (wr * 64 + ti * 16 + fr) * 128 + sw;
      yh[ks][ti] = *(const short8*)(Ah + off);
      yl[ks][ti] = *(const short8*)(Al + off);
    }
  }

#pragma unroll 1
  for (int plane = 0; plane < 2; ++plane) {
    if (plane == 1) {
      __syncthreads();   // all plane-0 B reads done
      stage16k(Bh, E1h + (size_t)bj * 128 * WD);
      stage16k(Bl, E1l + (size_t)bj * 128 * WD);
      __syncthreads();
    }
    const float* __restrict__ Xn = plane ? E1n : E2n;

    f32x4 acc[4][4] = {};   // [tj (n-tile)][ti (m-tile)]
#pragma unroll
    for (int ks = 0; ks < 2; ++ks) {
      const int sw = (ks * 64 + fg * 16) ^ ((fr & 7) << 4);
      short8 xh[4], xl[4];
#pragma unroll
      for (int tj = 0; tj < 4; ++tj) {
        const int off = (wc * 64 + tj * 16 + fr) * 128 + sw;
        xh[tj] = *(const short8*)(Bh + off);
        xl[tj] = *(const short8*)(Bl + off);
      }
#pragma unroll
      for (int tj = 0; tj < 4; ++tj)
#pragma unroll
        for (int ti = 0; ti < 4; ++ti) {
          acc[tj][ti] = __builtin_amdgcn_mfma_f32_16x16x32_bf16(xh[tj], yh[ks][ti], acc[tj][ti], 0, 0, 0);
          acc[tj][ti] = __builtin_amdgcn_mfma_f32_16x16x32_bf16(xh[tj], yl[ks][ti], acc[tj][ti], 0, 0, 0);
          acc[tj][ti] = __builtin_amdgcn_mfma_f32_16x16x32_bf16(xl[tj], yh[ks][ti], acc[tj][ti], 0, 0, 0);
          acc[tj][ti] = __builtin_amdgcn_mfma_f32_16x16x32_bf16(xl[tj], yl[ks][ti], acc[tj][ti], 0, 0, 0);
        }
    }

    // Epilogue (R4): reg r holds C[m][nb+r] -> f32x4 nontemporal store.
    const int row0 = bi * 128 + wr * 64;
    const int col0 = bj * 128 + wc * 64;
    float* __restrict__ o = out + (size_t)plane * N * N;
#pragma unroll
    for (int tj = 0; tj < 4; ++tj)
#pragma unroll
      for (int ti = 0; ti < 4; ++ti) {
        const int m  = row0 + ti * 16 + fr;
        const int nb = col0 + tj * 16 + fg * 4;
        const f32x4 v = acc[tj][ti];
        f32x4 sv;
#pragma unroll
        for (int r = 0; r < 4; ++r) {
          float val = v[r];
          if (fabsf(val - THRESH) < BAND)   // rare: exact f32 recompute
            val = exact_dot(E1n + (size_t)m * WD, Xn + (size_t)(nb + r) * WD);
          sv[r] = (val < THRESH) ? 0.f : val;
        }
        __builtin_nontemporal_store(sv, (f32x4*)(o + (size_t)m * N + nb));
      }
  }
}

extern "C" void kernel_launch(void* const* d_in, const int* in_sizes, int n_in,
                              void* d_out, int out_size, void* d_ws, size_t ws_size,
                              hipStream_t stream) {
  const float* fea1 = (const float*)d_in[0];
  const float* fea2 = (const float*)d_in[1];
  const float* w1   = (const float*)d_in[2];
  const float* w2   = (const float*)d_in[3];
  float* out = (float*)d_out;

  char* ws = (char*)d_ws;
  float*          E1n = (float*)(ws);                         // 2 MB
  float*          E2n = (float*)(ws + (2u << 20));            // 2 MB
  unsigned short* E1h = (unsigned short*)(ws + (4u << 20));   // 1 MB
  unsigned short* E1l = (unsigned short*)(ws + (5u << 20));   // 1 MB
  unsigned short* E2h = (unsigned short*)(ws + (6u << 20));   // 1 MB
  unsigned short* E2l = (unsigned short*)(ws + (7u << 20));   // 1 MB

  embed_norm<<<dim3(N / 32, 2), 256, 0, stream>>>(
      fea1, fea2, w1, w2, E1n, E2n, E1h, E1l, E2h, E2l);
  sim_mfma<<<dim3(64, 64), 256, 0, stream>>>(
      E1h, E1l, E2h, E2l, E1n, E2n, out);
}